// Round 8
// baseline (141.330 us; speedup 1.0000x reference)
//
#include <hip/hip_runtime.h>
#include <hip/hip_bf16.h>
#include <math.h>

// HIR rainfall-runoff scan — tolerance-bracketed time-chunking + exact fixup.
//
// V9 changes vs V8 (129.6 us; pass1 54.6 us regression from PIPE4):
//  * Revert PIPE4 -> PIPE3 (V8: more live buffers + clamped tail re-loads
//    cost more than W's -14% work saved). Keep W=320.
//  * Dual-row ILP: each thread runs TWO independent chunk-tasks, (b,c) and
//    (b+B/2,c) — same c => identical warm-up mode/length, zero divergence,
//    zero redundant work. The two chains interleave in the issue stream so
//    one chain's dep-latency stalls are filled by the other's issue.
//    Rationale: across V2/V4/V6/V7/V8 issue time is pinned ~20 us and the
//    ~30 us stall is insensitive to layout/prefetch/stores; the only lever
//    that moved per-SIMD throughput was a 2nd context (V5: 325->183 cy per
//    wave-step marginal, but V5 paid 1.8x work for it; this pays zero).
//  * Grid halves to 512 waves (0.5/SIMD): time is per-wave, not per-SIMD.
//    Two LDS store-transpose tiles (33 KB, 2 blocks/CU OK).
//
// Q[b,t] (t>=1) = fluxes from carry entering step t; Q[b,0] uses the FINAL
// carry (jnp.roll wraparound) with t=0 inputs (chunk NC-1 owner writes it).

struct P {
    float INSC, SMSC, RecK, g1, lc, k1, k2, k3, c2;
};

__device__ __forceinline__ P make_params(const float* pINSC, const float* pCOEFF,
                                         const float* pSQ,   const float* pSMSC,
                                         const float* pSUB,  const float* pCRAK,
                                         const float* pRecK) {
    P p;
    p.INSC      = fminf(fmaxf(pINSC[0]  * 5.0f,   0.5f),   5.0f);
    float COEFF = fminf(fmaxf(pCOEFF[0] * 400.0f, 50.0f),  400.0f);
    float SQ    = fminf(fmaxf(pSQ[0]    * 6.0f,   0.0f),   6.0f);
    p.SMSC      = fminf(fmaxf(pSMSC[0]  * 500.0f, 50.0f),  500.0f);
    float SUB   = fminf(fmaxf(pSUB[0],  0.0f), 1.0f);
    float CRAK  = fminf(fmaxf(pCRAK[0], 0.0f), 1.0f);
    p.RecK      = fminf(fmaxf(pRecK[0]  * 0.3f,   0.003f), 0.3f);
    p.g1 = 1.0f - p.RecK;
    p.lc = log2f(COEFF);
    float inv = 1.0f / p.SMSC;
    p.k1 = SUB * inv;
    p.k2 = CRAK * inv;
    p.k3 = 10.0f * inv;
    p.c2 = (-SQ * inv) * 1.44269504088896340736f;
    return p;
}

// Full step with Q. Critical sms chain: fminf -> fmaf -> exp2f -> fminf ->
// mul -> fmaf. Everything else is off-path.
__device__ __forceinline__ float step(float Prec, float PET, float& sms, float& gw, const P& p) {
    float INT  = fminf(fminf(p.INSC, PET), Prec);
    float INR  = Prec - INT;
    float POT  = PET - INT;
    float S    = fminf(sms, p.SMSC);                 // lower clamp provably slack
    float u    = fmaf(-p.k1, S, 1.0f);
    float v    = fmaf(-p.k2, S, 1.0f);
    float ETS  = fminf(POT, p.k3 * S);
    float SmE  = S - ETS;
    float e    = exp2f(fmaf(p.c2, S, p.lc));         // cap = COEFF*2^(c2*S)
    float RMO  = fminf(INR, e);
    float w    = u * RMO;                            // t2 = RMO - SRUN
    float s2   = fmaf(v, w, SmE);                    // S + SMF - ETS
    float SMF  = v * w;
    float REC  = w - SMF;
    float RECnew = REC + fmaxf(s2 - p.SMSC, 0.0f);
    float BAS  = p.RecK * gw;
    float Q    = (INR - w) + BAS;                    // IRUN + SRUN + BAS
    gw  = fmaf(p.g1, gw, RECnew);
    sms = s2;
    return Q;
}

// Warm-up / state-advance step without Q (single chain, carries gw).
__device__ __forceinline__ void stepw(float Prec, float PET, float& sms, float& gw, const P& p) {
    float INT  = fminf(fminf(p.INSC, PET), Prec);
    float INR  = Prec - INT;
    float POT  = PET - INT;
    float S    = fminf(sms, p.SMSC);
    float u    = fmaf(-p.k1, S, 1.0f);
    float v    = fmaf(-p.k2, S, 1.0f);
    float ETS  = fminf(POT, p.k3 * S);
    float SmE  = S - ETS;
    float e    = exp2f(fmaf(p.c2, S, p.lc));
    float RMO  = fminf(INR, e);
    float w    = u * RMO;
    float s2   = fmaf(v, w, SmE);
    float SMF  = v * w;
    float REC  = w - SMF;
    float RECnew = REC + fmaxf(s2 - p.SMSC, 0.0f);
    gw  = fmaf(p.g1, gw, RECnew);
    sms = s2;
}

// Dual-bracket warm-up step: hi chain carries gw; lo chain is sms-only.
// Shares INT/INR/POT between the chains.
__device__ __forceinline__ void dstep(float Prec, float PET,
                                      float& slo, float& shi, float& gw, const P& p) {
    float INT = fminf(fminf(p.INSC, PET), Prec);
    float INR = Prec - INT;
    float POT = PET - INT;
    {   // hi + gw
        float S    = fminf(shi, p.SMSC);
        float u    = fmaf(-p.k1, S, 1.0f);
        float v    = fmaf(-p.k2, S, 1.0f);
        float ETS  = fminf(POT, p.k3 * S);
        float SmE  = S - ETS;
        float e    = exp2f(fmaf(p.c2, S, p.lc));
        float RMO  = fminf(INR, e);
        float w    = u * RMO;
        float s2   = fmaf(v, w, SmE);
        float SMF  = v * w;
        float REC  = w - SMF;
        float RECnew = REC + fmaxf(s2 - p.SMSC, 0.0f);
        gw  = fmaf(p.g1, gw, RECnew);
        shi = s2;
    }
    {   // lo, sms only
        float S    = fminf(slo, p.SMSC);
        float u    = fmaf(-p.k1, S, 1.0f);
        float v    = fmaf(-p.k2, S, 1.0f);
        float ETS  = fminf(POT, p.k3 * S);
        float SmE  = S - ETS;
        float e    = exp2f(fmaf(p.c2, S, p.lc));
        float RMO  = fminf(INR, e);
        float w    = u * RMO;
        slo = fmaf(v, w, SmE);
    }
}

#define MERGE_TOL 0.75f

// ---------------------------------------------------------------------------
// Single-stream 3-buffer pipeline (fixup). Ambient: bp, B0..B2.
// ---------------------------------------------------------------------------

#define LBS(DST, K, NB) do { int _kn = (K) < (NB) ? (K) : (NB) - 1;             \
    _Pragma("unroll") for (int _q = 0; _q < 4; ++_q) DST[_q] = bp[4 * _kn + _q]; } while (0)

#define PIPE3S(NB, CB) do { if ((NB) > 0) {                                     \
    LBS(B0, 0, (NB)); LBS(B1, 1, (NB));                                         \
    int _j = 0;                                                                 \
    for (; _j + 3 <= (NB); _j += 3) {                                           \
        LBS(B2, _j + 2, (NB)); CB(B0, _j);                                      \
        LBS(B0, _j + 3, (NB)); CB(B1, _j + 1);                                  \
        LBS(B1, _j + 4, (NB)); CB(B2, _j + 2);                                  \
    }                                                                           \
    if (_j < (NB)) { LBS(B2, _j + 2, (NB)); CB(B0, _j); ++_j;                   \
        if (_j < (NB)) { LBS(B0, _j + 2, (NB)); CB(B1, _j); } }                 \
} } while (0)

#define CBW1(BUF, J) do { _Pragma("unroll") for (int _m = 0; _m < 4; ++_m) {    \
    stepw(BUF[_m].x, BUF[_m].y, shi, gw, p);                                    \
    stepw(BUF[_m].z, BUF[_m].w, shi, gw, p); } } while (0)

#define CBF1(BUF, J) do { _Pragma("unroll") for (int _m = 0; _m < 4; ++_m) {    \
    float _qa = step(BUF[_m].x, BUF[_m].y, sms, gw, p);                         \
    float _qb = step(BUF[_m].z, BUF[_m].w, sms, gw, p);                         \
    orow2[ib0 + 4 * (J) + _m] = make_float2(_qa, _qb); } } while (0)

// ---------------------------------------------------------------------------
// Dual-stream 3-buffer pipeline (pass1). Ambient: bpA/bpB, A0..A2 / Z0..Z2.
// Batch j lives in buffer j%3; load for j+2 issues in slot j. All NB values
// are in {0,8,16,24,32,40}; clamped tail loads only overwrite consumed
// buffers (same schedule as V7, verified).
// ---------------------------------------------------------------------------

#define LBD(DA, DZ, K, NB) do { int _kn = (K) < (NB) ? (K) : (NB) - 1;          \
    _Pragma("unroll") for (int _q = 0; _q < 4; ++_q) {                          \
        DA[_q] = bpA[4 * _kn + _q]; DZ[_q] = bpB[4 * _kn + _q]; } } while (0)

#define PIPE3D(NB, CB) do { if ((NB) > 0) {                                     \
    LBD(A0, Z0, 0, (NB)); LBD(A1, Z1, 1, (NB));                                 \
    int _j = 0;                                                                 \
    for (; _j + 3 <= (NB); _j += 3) {                                           \
        LBD(A2, Z2, _j + 2, (NB)); CB(A0, Z0, _j);                              \
        LBD(A0, Z0, _j + 3, (NB)); CB(A1, Z1, _j + 1);                          \
        LBD(A1, Z1, _j + 4, (NB)); CB(A2, Z2, _j + 2);                          \
    }                                                                           \
    if (_j < (NB)) { LBD(A2, Z2, _j + 2, (NB)); CB(A0, Z0, _j); ++_j;           \
        if (_j < (NB)) { LBD(A0, Z0, _j + 2, (NB)); CB(A1, Z1, _j); } }         \
} } while (0)

// Dual compute-batch macros: interleave the two independent streams.
#define CBW2(BA, BZ, J) do { _Pragma("unroll") for (int _m = 0; _m < 4; ++_m) { \
    stepw(BA[_m].x, BA[_m].y, shiA, gwA, p);                                    \
    stepw(BZ[_m].x, BZ[_m].y, shiB, gwB, p);                                    \
    stepw(BA[_m].z, BA[_m].w, shiA, gwA, p);                                    \
    stepw(BZ[_m].z, BZ[_m].w, shiB, gwB, p); } } while (0)

#define CBD2(BA, BZ, J) do { _Pragma("unroll") for (int _m = 0; _m < 4; ++_m) { \
    dstep(BA[_m].x, BA[_m].y, sloA, shiA, gwA, p);                              \
    dstep(BZ[_m].x, BZ[_m].y, sloB, shiB, gwB, p);                              \
    dstep(BA[_m].z, BA[_m].w, sloA, shiA, gwA, p);                              \
    dstep(BZ[_m].z, BZ[_m].w, sloB, shiB, gwB, p); } } while (0)

#define CBM2(BA, BZ, J) do { int _tb = 8 * (J);                                 \
    _Pragma("unroll") for (int _m = 0; _m < 4; ++_m) {                          \
    float _qa = step(BA[_m].x, BA[_m].y, smsA, gwA, p);                         \
    float _qc = step(BZ[_m].x, BZ[_m].y, smsB, gwB, p);                         \
    float _qb = step(BA[_m].z, BA[_m].w, smsA, gwA, p);                         \
    float _qd = step(BZ[_m].z, BZ[_m].w, smsB, gwB, p);                         \
    lds_qA[_tb + 2 * _m][l] = _qa; lds_qA[_tb + 2 * _m + 1][l] = _qb;           \
    lds_qB[_tb + 2 * _m][l] = _qc; lds_qB[_tb + 2 * _m + 1][l] = _qd; } } while (0)

// ---------------------------------------------------------------------------
// Pass 1 (dual-row): thread handles (b, c) and (b+H, c), H = B/2.
// Lanes = 64 consecutive b; c wave-uniform (H % 64 == 0).
// ---------------------------------------------------------------------------

template<int T, int NC, int W>
__global__ __launch_bounds__(64, 1)
void hir_pass1(const float* __restrict__ inputs,
               const float* __restrict__ pINSC,  const float* __restrict__ pCOEFF,
               const float* __restrict__ pSQ,    const float* __restrict__ pSMSC,
               const float* __restrict__ pSUB,   const float* __restrict__ pCRAK,
               const float* __restrict__ pRecK,
               float* __restrict__ out, float4* __restrict__ st, int B)
{
    __shared__ float lds_qA[64][65];
    __shared__ float lds_qB[64][65];
    const int l   = threadIdx.x;
    const int gid = blockIdx.x * 64 + l;
    const int H = B >> 1;
    const int b = gid % H;                 // stream-A row; stream-B row = b+H
    const int c = gid / H;                 // wave-uniform (H % 64 == 0)
    if (c >= NC) return;

    P p = make_params(pINSC, pCOEFF, pSQ, pSMSC, pSUB, pCRAK, pRecK);

    const float4* __restrict__ rpA = (const float4*)(inputs + (size_t)b * (2 * T));
    const float4* __restrict__ rpB = (const float4*)(inputs + (size_t)(b + H) * (2 * T));
    float* __restrict__ orowA = out + (size_t)b * T;
    float* __restrict__ orowB = out + (size_t)(b + H) * T;

    constexpr int CH = T / NC;             // 64 steps
    const int i1 = (c * CH) >> 1;          // first main float4 index
    int i0 = i1 - (W >> 1);                // warm-up start (W/2 float4s)
    const bool exact = (i0 <= 0);
    if (i0 < 0) i0 = 0;

    float sloA = 0.0f, shiA = exact ? 0.0f : p.SMSC, gwA = 0.0f;
    float sloB = 0.0f, shiB = exact ? 0.0f : p.SMSC, gwB = 0.0f;
    float4 A0[4], A1[4], A2[4], Z0[4], Z1[4], Z2[4];

    // ---- Warm-up: both streams, identical length/mode ----
    {
        const int nb = (i1 - i0) >> 2;     // in {0, 8, 16, 24, 32, 40}
        const float4* bpA = rpA + i0;
        const float4* bpB = rpB + i0;
        if (exact) {
            PIPE3D(nb, CBW2);              // true chains
            sloA = shiA; sloB = shiB;
        } else {
            PIPE3D(nb, CBD2);              // bracket chains
        }
    }
    const bool mergedA = exact || ((shiA - sloA) <= MERGE_TOL);
    const bool mergedB = exact || ((shiB - sloB) <= MERGE_TOL);
    float smsA = exact ? shiA : (0.5f * (sloA + shiA));
    float smsB = exact ? shiB : (0.5f * (sloB + shiB));

    // ---- Main chunk: 8 batches, Q -> LDS tiles ----
    {
        const float4* bpA = rpA + i1;
        const float4* bpB = rpB + i1;
        PIPE3D(8, CBM2);
    }

    st[(size_t)c * B + b]     = make_float4(smsA, gwA, mergedA ? 1.0f : 0.0f, 0.0f);
    st[(size_t)c * B + b + H] = make_float4(smsB, gwB, mergedB ? 1.0f : 0.0f, 0.0f);

    // Q[b,0] from the final carry (jnp.roll wraparound), owned by chunk NC-1.
    float q0A = 0.0f, q0B = 0.0f;
    const bool hasq0 = (c == NC - 1);
    if (hasq0) {
        float4 f0 = rpA[0];
        float ss = smsA, gg = gwA;
        q0A = step(f0.x, f0.y, ss, gg, p);
        float4 g0 = rpB[0];
        float tt = smsB, hh = gwB;
        q0B = step(g0.x, g0.y, tt, hh, p);
    }

    __syncthreads();

    // ---- Store phase: coalesced columns for both tiles ----
    const int b0 = b - l;                  // wave base row (H % 64 == 0)
    const int t1 = c * CH;
    if (c == 0) {
        if (l > 0) {                       // lane 0 would write t=0 (owned by roll)
            for (int j = 0; j < 64; ++j) {
                out[(size_t)(b0 + j) * T + l]     = lds_qA[l][j];
                out[(size_t)(b0 + H + j) * T + l] = lds_qB[l][j];
            }
        }
    } else {
        for (int j = 0; j < 64; ++j) {
            out[(size_t)(b0 + j) * T + t1 + l]     = lds_qA[l][j];
            out[(size_t)(b0 + H + j) * T + t1 + l] = lds_qB[l][j];
        }
    }
    if (hasq0) { orowA[0] = q0A; orowB[0] = q0B; }
}

// ---------------------------------------------------------------------------
// Fixup: thread per (b, c). Merged -> one coalesced st read, exit. Unmerged
// -> walk back to nearest merged predecessor m (chunk 0 always exact =>
// merged), advance store-free through m+1..c-1, recompute chunk c exactly
// with direct out stores. PIPE3 loads. Same semantics as sequential fixup.
// ---------------------------------------------------------------------------

template<int T, int NC>
__global__ __launch_bounds__(64)
void hir_fixup(const float* __restrict__ inputs,
               const float* __restrict__ pINSC,  const float* __restrict__ pCOEFF,
               const float* __restrict__ pSQ,    const float* __restrict__ pSMSC,
               const float* __restrict__ pSUB,   const float* __restrict__ pCRAK,
               const float* __restrict__ pRecK,
               float* __restrict__ out, const float4* __restrict__ st, int B)
{
    const int gid = blockIdx.x * 64 + threadIdx.x;
    const int b = gid % B;
    const int c = gid / B;
    if (c >= NC) return;

    float4 sc = st[(size_t)c * B + b];
    if (sc.z != 0.0f) return;              // merged -> nothing to fix

    P p = make_params(pINSC, pCOEFF, pSQ, pSMSC, pSUB, pCRAK, pRecK);
    constexpr int CH = T / NC;

    const float4* __restrict__ rp = (const float4*)(inputs + (size_t)b * (2 * T));
    float* __restrict__ orow = out + (size_t)b * T;
    float2* __restrict__ orow2 = (float2*)orow;

    // Walk back to nearest merged predecessor (c >= 1 here: chunk 0 merged).
    int m = c - 1;
    float4 sm = st[(size_t)m * B + b];
    while (sm.z == 0.0f) { --m; sm = st[(size_t)m * B + b]; }
    float sms = sm.x, gw = sm.y;

    float4 B0[4], B1[4], B2[4];

    // Advance state through chunks m+1..c-1 (no stores), pipelined.
    {
        const int ia = ((m + 1) * CH) >> 1;
        const int ibx = (c * CH) >> 1;
        const int nb = (ibx - ia) >> 2;    // multiple of 8 (or 0)
        const float4* bp = rp + ia;
        float& shi = sms;                  // CBW1 advances "shi"
        PIPE3S(nb, CBW1);
    }

    // Recompute chunk c exactly, with stores, pipelined.
    {
        const int ib0 = (c * CH) >> 1;     // float2 output base index
        const float4* bp = rp + ib0;
        PIPE3S(8, CBF1);
    }

    if (c == NC - 1) {                     // rewrite the t=0 wraparound output
        float4 f0 = rp[0];
        float ss = sms, gg = gw;
        orow[0] = step(f0.x, f0.y, ss, gg, p);
    }
}

// Fallback: monolithic sequential (odd shapes / tiny workspace).
template<int T>
__global__ __launch_bounds__(64, 1)
void hir_scan_kernel(const float* __restrict__ inputs,
                     const float* __restrict__ pINSC,  const float* __restrict__ pCOEFF,
                     const float* __restrict__ pSQ,    const float* __restrict__ pSMSC,
                     const float* __restrict__ pSUB,   const float* __restrict__ pCRAK,
                     const float* __restrict__ pRecK,
                     float* __restrict__ out, int B)
{
    int b = blockIdx.x * blockDim.x + threadIdx.x;
    if (b >= B) return;
    P p = make_params(pINSC, pCOEFF, pSQ, pSMSC, pSUB, pCRAK, pRecK);
    const float4* __restrict__ rp = (const float4*)(inputs + (size_t)b * (2 * T));
    float* __restrict__ orow = out + (size_t)b * T;
    float sms = 0.0f, gw = 0.0f;
    float4 cur = rp[0];
    const float P0 = cur.x, E0 = cur.y;
    constexpr int NI = T / 2;
    for (int i = 0; i < NI; ++i) {
        int ni = (i + 1 < NI) ? (i + 1) : i;
        float4 nxt = rp[ni];
        float qa = step(cur.x, cur.y, sms, gw, p);
        float qb = step(cur.z, cur.w, sms, gw, p);
        if (i == 0) { orow[1] = qb; }
        else        { ((float2*)orow)[i] = make_float2(qa, qb); }
        cur = nxt;
    }
    float ss = sms, gg = gw;
    orow[0] = step(P0, E0, ss, gg, p);
}

extern "C" void kernel_launch(void* const* d_in, const int* in_sizes, int n_in,
                              void* d_out, int out_size, void* d_ws, size_t ws_size,
                              hipStream_t stream) {
    (void)n_in; (void)out_size;
    constexpr int T  = 1024;
    constexpr int NC = 16;    // chunks (CH=64)
    constexpr int W  = 320;   // warm-up: gap ~250*e^(-.0201*320) ~ 0.4 < 0.75
    const float* inputs = (const float*)d_in[0];
    const float* INSC   = (const float*)d_in[1];
    const float* COEFF  = (const float*)d_in[2];
    const float* SQ     = (const float*)d_in[3];
    const float* SMSC   = (const float*)d_in[4];
    const float* SUB    = (const float*)d_in[5];
    const float* CRAK   = (const float*)d_in[6];
    const float* RecK   = (const float*)d_in[7];
    float* out = (float*)d_out;

    int B = in_sizes[0] / (2 * T);            // 4096 for the reference shape
    size_t stBytes = (size_t)B * NC * sizeof(float4);   // 1 MB

    if ((B % 128) == 0 && ws_size >= stBytes) {
        float4* st = (float4*)d_ws;
        long totalP = (long)(B / 2) * NC;     // 32768 threads = 512 waves
        int blocksP = (int)((totalP + 63) / 64);
        hir_pass1<T, NC, W><<<dim3(blocksP), dim3(64), 0, stream>>>(
            inputs, INSC, COEFF, SQ, SMSC, SUB, CRAK, RecK, out, st, B);
        long totalF = (long)B * NC;
        int blocksF = (int)((totalF + 63) / 64);
        hir_fixup<T, NC><<<dim3(blocksF), dim3(64), 0, stream>>>(
            inputs, INSC, COEFF, SQ, SMSC, SUB, CRAK, RecK, out, st, B);
        return;
    }

    int blocks = (B + 63) / 64;
    hir_scan_kernel<T><<<dim3(blocks), dim3(64), 0, stream>>>(
        inputs, INSC, COEFF, SQ, SMSC, SUB, CRAK, RecK, out, B);
}

// Round 9
// 117.422 us; speedup vs baseline: 1.2036x; 1.2036x over previous
//
#include <hip/hip_runtime.h>
#include <hip/hip_bf16.h>
#include <math.h>

// HIR rainfall-runoff scan — tolerance-bracketed time-chunking + exact fixup.
//
// V10 = V7 (best pass1 structure, 48.5 us @ W=384) with ONE change: W=320.
//  * V8 post-mortem: V8 bundled {PIPE4, W 384->320} and regressed; the
//    regression was PIPE4's (+20 VGPR, clamped tail reloads). W=320 on the
//    PIPE3 structure was never measured alone. It is -14% steps/thread
//    (448 -> 384) in V2's 4x-validated tolerance regime (gap ~0.4 < 0.75).
//  * Machine model from V5/V7/V9: per-wave step cost ~260-300 cy (latency-
//    type, per chain); 2-wave/SIMD co-residency free; 2-way ILP = 1.47x
//    per-wave but requires halving waves (net loss). Best remains 1024
//    waves x 1 chain/thread; the only clean lever left is step count.
//  * Fixup: thread-per-(b,c), early-exit merged. At mostly-merged rates the
//    walk-back predecessor is ~always c-1 (advance length 0) so the fixup
//    critical path is ~64-128 serial steps, insensitive to W.
//
// Q[b,t] (t>=1) = fluxes from carry entering step t; Q[b,0] uses the FINAL
// carry (jnp.roll wraparound) with t=0 inputs (chunk NC-1 owner writes it).

struct P {
    float INSC, SMSC, RecK, g1, lc, k1, k2, k3, c2;
    // g1=1-RecK, lc=log2(COEFF), k1=SUB/SMSC, k2=CRAK/SMSC, k3=10/SMSC,
    // c2=-SQ/SMSC*log2(e)
};

__device__ __forceinline__ P make_params(const float* pINSC, const float* pCOEFF,
                                         const float* pSQ,   const float* pSMSC,
                                         const float* pSUB,  const float* pCRAK,
                                         const float* pRecK) {
    P p;
    p.INSC      = fminf(fmaxf(pINSC[0]  * 5.0f,   0.5f),   5.0f);
    float COEFF = fminf(fmaxf(pCOEFF[0] * 400.0f, 50.0f),  400.0f);
    float SQ    = fminf(fmaxf(pSQ[0]    * 6.0f,   0.0f),   6.0f);
    p.SMSC      = fminf(fmaxf(pSMSC[0]  * 500.0f, 50.0f),  500.0f);
    float SUB   = fminf(fmaxf(pSUB[0],  0.0f), 1.0f);
    float CRAK  = fminf(fmaxf(pCRAK[0], 0.0f), 1.0f);
    p.RecK      = fminf(fmaxf(pRecK[0]  * 0.3f,   0.003f), 0.3f);
    p.g1 = 1.0f - p.RecK;
    p.lc = log2f(COEFF);
    float inv = 1.0f / p.SMSC;
    p.k1 = SUB * inv;
    p.k2 = CRAK * inv;
    p.k3 = 10.0f * inv;
    p.c2 = (-SQ * inv) * 1.44269504088896340736f;
    return p;
}

// Full step with Q. Critical sms chain: fminf -> fmaf -> exp2f -> fminf ->
// mul -> fmaf. Everything else is off-path.
__device__ __forceinline__ float step(float Prec, float PET, float& sms, float& gw, const P& p) {
    float INT  = fminf(fminf(p.INSC, PET), Prec);
    float INR  = Prec - INT;
    float POT  = PET - INT;
    float S    = fminf(sms, p.SMSC);                 // lower clamp provably slack
    float u    = fmaf(-p.k1, S, 1.0f);
    float v    = fmaf(-p.k2, S, 1.0f);
    float ETS  = fminf(POT, p.k3 * S);
    float SmE  = S - ETS;
    float e    = exp2f(fmaf(p.c2, S, p.lc));         // cap = COEFF*2^(c2*S)
    float RMO  = fminf(INR, e);
    float w    = u * RMO;                            // t2 = RMO - SRUN
    float s2   = fmaf(v, w, SmE);                    // S + SMF - ETS
    float SMF  = v * w;
    float REC  = w - SMF;
    float RECnew = REC + fmaxf(s2 - p.SMSC, 0.0f);
    float BAS  = p.RecK * gw;
    float Q    = (INR - w) + BAS;                    // IRUN + SRUN + BAS
    gw  = fmaf(p.g1, gw, RECnew);
    sms = s2;
    return Q;
}

// Warm-up / state-advance step without Q (single chain, carries gw).
__device__ __forceinline__ void stepw(float Prec, float PET, float& sms, float& gw, const P& p) {
    float INT  = fminf(fminf(p.INSC, PET), Prec);
    float INR  = Prec - INT;
    float POT  = PET - INT;
    float S    = fminf(sms, p.SMSC);
    float u    = fmaf(-p.k1, S, 1.0f);
    float v    = fmaf(-p.k2, S, 1.0f);
    float ETS  = fminf(POT, p.k3 * S);
    float SmE  = S - ETS;
    float e    = exp2f(fmaf(p.c2, S, p.lc));
    float RMO  = fminf(INR, e);
    float w    = u * RMO;
    float s2   = fmaf(v, w, SmE);
    float SMF  = v * w;
    float REC  = w - SMF;
    float RECnew = REC + fmaxf(s2 - p.SMSC, 0.0f);
    gw  = fmaf(p.g1, gw, RECnew);
    sms = s2;
}

// Dual-bracket warm-up step: hi chain carries gw; lo chain is sms-only.
// Shares INT/INR/POT between the chains.
__device__ __forceinline__ void dstep(float Prec, float PET,
                                      float& slo, float& shi, float& gw, const P& p) {
    float INT = fminf(fminf(p.INSC, PET), Prec);
    float INR = Prec - INT;
    float POT = PET - INT;
    {   // hi + gw
        float S    = fminf(shi, p.SMSC);
        float u    = fmaf(-p.k1, S, 1.0f);
        float v    = fmaf(-p.k2, S, 1.0f);
        float ETS  = fminf(POT, p.k3 * S);
        float SmE  = S - ETS;
        float e    = exp2f(fmaf(p.c2, S, p.lc));
        float RMO  = fminf(INR, e);
        float w    = u * RMO;
        float s2   = fmaf(v, w, SmE);
        float SMF  = v * w;
        float REC  = w - SMF;
        float RECnew = REC + fmaxf(s2 - p.SMSC, 0.0f);
        gw  = fmaf(p.g1, gw, RECnew);
        shi = s2;
    }
    {   // lo, sms only
        float S    = fminf(slo, p.SMSC);
        float u    = fmaf(-p.k1, S, 1.0f);
        float v    = fmaf(-p.k2, S, 1.0f);
        float ETS  = fminf(POT, p.k3 * S);
        float SmE  = S - ETS;
        float e    = exp2f(fmaf(p.c2, S, p.lc));
        float RMO  = fminf(INR, e);
        float w    = u * RMO;
        slo = fmaf(v, w, SmE);
    }
}

#define MERGE_TOL 0.75f

// ---------------------------------------------------------------------------
// 3-buffer, 4-float4-batch software pipeline (distance-2, no register copies).
// Ambient names used by the macros: bp (const float4* batch base), B0/B1/B2
// (float4[4] buffers), plus whatever state the CB compute macro references.
// Invariant: batch j's data is in B[j%3]; the load for batch j+2 is issued in
// batch j's slot. Clamped tail loads always target already-consumed buffers.
// ---------------------------------------------------------------------------

#define LB(DST, K, NB) do { int _kn = (K) < (NB) ? (K) : (NB) - 1;              \
    _Pragma("unroll") for (int _q = 0; _q < 4; ++_q) DST[_q] = bp[4 * _kn + _q]; } while (0)

#define PIPE3(NB, CB) do { if ((NB) > 0) {                                      \
    LB(B0, 0, (NB)); LB(B1, 1, (NB));                                           \
    int _j = 0;                                                                 \
    for (; _j + 3 <= (NB); _j += 3) {                                           \
        LB(B2, _j + 2, (NB)); CB(B0, _j);                                       \
        LB(B0, _j + 3, (NB)); CB(B1, _j + 1);                                   \
        LB(B1, _j + 4, (NB)); CB(B2, _j + 2);                                   \
    }                                                                           \
    if (_j < (NB)) { LB(B2, _j + 2, (NB)); CB(B0, _j); ++_j;                    \
        if (_j < (NB)) { LB(B0, _j + 2, (NB)); CB(B1, _j); } }                  \
} } while (0)

// Compute-batch macros (8 steps per batch).
#define CBW(BUF, J) do { _Pragma("unroll") for (int _m = 0; _m < 4; ++_m) {     \
    stepw(BUF[_m].x, BUF[_m].y, shi, gw, p);                                    \
    stepw(BUF[_m].z, BUF[_m].w, shi, gw, p); } } while (0)

#define CBD(BUF, J) do { _Pragma("unroll") for (int _m = 0; _m < 4; ++_m) {     \
    dstep(BUF[_m].x, BUF[_m].y, slo, shi, gw, p);                               \
    dstep(BUF[_m].z, BUF[_m].w, slo, shi, gw, p); } } while (0)

#define CBM(BUF, J) do { int _tb = 8 * (J);                                     \
    _Pragma("unroll") for (int _m = 0; _m < 4; ++_m) {                          \
    float _qa = step(BUF[_m].x, BUF[_m].y, sms, gw, p);                         \
    float _qb = step(BUF[_m].z, BUF[_m].w, sms, gw, p);                         \
    lds_q[_tb + 2 * _m][l] = _qa; lds_q[_tb + 2 * _m + 1][l] = _qb; } } while (0)

#define CBF(BUF, J) do { _Pragma("unroll") for (int _m = 0; _m < 4; ++_m) {     \
    float _qa = step(BUF[_m].x, BUF[_m].y, sms, gw, p);                         \
    float _qb = step(BUF[_m].z, BUF[_m].w, sms, gw, p);                         \
    orow2[ib0 + 4 * (J) + _m] = make_float2(_qa, _qb); } } while (0)

// ---------------------------------------------------------------------------
// Pass 1: one thread per (b, c); lanes = 64 consecutive b, c wave-uniform.
// Q buffered in LDS and written coalesced (store-transpose).
// ---------------------------------------------------------------------------

template<int T, int NC, int W>
__global__ __launch_bounds__(64, 1)
void hir_pass1(const float* __restrict__ inputs,
               const float* __restrict__ pINSC,  const float* __restrict__ pCOEFF,
               const float* __restrict__ pSQ,    const float* __restrict__ pSMSC,
               const float* __restrict__ pSUB,   const float* __restrict__ pCRAK,
               const float* __restrict__ pRecK,
               float* __restrict__ out, float4* __restrict__ st, int B)
{
    __shared__ float lds_q[64][65];        // [t_local][lane], +1 pad: bank-free
    const int l   = threadIdx.x;
    const int gid = blockIdx.x * 64 + l;
    const int b = gid % B;                 // consecutive lanes -> consecutive rows
    const int c = gid / B;                 // wave-uniform (B % 64 == 0)
    if (c >= NC) return;                   // never taken for the exact grid

    P p = make_params(pINSC, pCOEFF, pSQ, pSMSC, pSUB, pCRAK, pRecK);

    const float4* __restrict__ rp = (const float4*)(inputs + (size_t)b * (2 * T));
    float* __restrict__ orow = out + (size_t)b * T;

    constexpr int CH = T / NC;             // 64 steps
    const int i1 = (c * CH) >> 1;          // first main float4 index
    int i0 = i1 - (W >> 1);                // warm-up start (W/2 float4s)
    const bool exact = (i0 <= 0);
    if (i0 < 0) i0 = 0;

    float slo = 0.0f, shi = exact ? 0.0f : p.SMSC, gw = 0.0f;
    float4 B0[4], B1[4], B2[4];

    // ---- Warm-up: pipelined batches (8 steps each), wave-uniform branch ----
    {
        const int nb = (i1 - i0) >> 2;     // in {0, 8, 16, 24, 32, 40}
        const float4* bp = rp + i0;
        if (exact) {
            PIPE3(nb, CBW);                // advances shi (true chain)
            slo = shi;
        } else {
            PIPE3(nb, CBD);                // dual bracket chains
        }
    }
    const bool merged = exact || ((shi - slo) <= MERGE_TOL);
    float sms = exact ? shi : (0.5f * (slo + shi));

    // ---- Main chunk: 8 batches, Q -> LDS (bank-conflict-free) ----
    {
        const float4* bp = rp + i1;
        PIPE3(8, CBM);
    }

    st[(size_t)c * B + b] = make_float4(sms, gw, merged ? 1.0f : 0.0f, 0.0f);

    // Q[b,0] from the final carry (jnp.roll wraparound), owned by chunk NC-1.
    float q0 = 0.0f;
    const bool hasq0 = (c == NC - 1);
    if (hasq0) {
        float4 f0 = rp[0];
        float ss = sms, gg = gw;
        q0 = step(f0.x, f0.y, ss, gg, p);
    }

    __syncthreads();                       // lds_q visible across the wave

    // ---- Store phase: coalesced columns. out[b0+j][t1+l] = lds_q[l][j] ----
    const int b0 = b - l;                  // wave base row (B % 64 == 0)
    const int t1 = c * CH;
    if (c == 0) {
        if (l > 0) {                       // lane 0 would write t=0 (owned by roll)
            for (int j = 0; j < 64; ++j)
                out[(size_t)(b0 + j) * T + l] = lds_q[l][j];
        }
    } else {
        for (int j = 0; j < 64; ++j)
            out[(size_t)(b0 + j) * T + t1 + l] = lds_q[l][j];
    }
    if (hasq0) orow[0] = q0;
}

// ---------------------------------------------------------------------------
// Fixup: thread per (b, c). Merged -> one coalesced st read, exit. Unmerged
// -> walk back to nearest merged predecessor m (chunk 0 is always exact =>
// merged), advance store-free through m+1..c-1, recompute chunk c exactly
// with direct out stores. Pipelined loads throughout. Same semantics as the
// sequential per-row fixup: merged states are accepted as-is.
// ---------------------------------------------------------------------------

template<int T, int NC>
__global__ __launch_bounds__(64)
void hir_fixup(const float* __restrict__ inputs,
               const float* __restrict__ pINSC,  const float* __restrict__ pCOEFF,
               const float* __restrict__ pSQ,    const float* __restrict__ pSMSC,
               const float* __restrict__ pSUB,   const float* __restrict__ pCRAK,
               const float* __restrict__ pRecK,
               float* __restrict__ out, const float4* __restrict__ st, int B)
{
    const int gid = blockIdx.x * 64 + threadIdx.x;
    const int b = gid % B;
    const int c = gid / B;
    if (c >= NC) return;

    float4 sc = st[(size_t)c * B + b];
    if (sc.z != 0.0f) return;              // merged -> nothing to fix

    P p = make_params(pINSC, pCOEFF, pSQ, pSMSC, pSUB, pCRAK, pRecK);
    constexpr int CH = T / NC;

    const float4* __restrict__ rp = (const float4*)(inputs + (size_t)b * (2 * T));
    float* __restrict__ orow = out + (size_t)b * T;
    float2* __restrict__ orow2 = (float2*)orow;

    // Walk back to nearest merged predecessor (c >= 1 here: chunk 0 merged).
    int m = c - 1;
    float4 sm = st[(size_t)m * B + b];
    while (sm.z == 0.0f) { --m; sm = st[(size_t)m * B + b]; }
    float sms = sm.x, gw = sm.y;

    float4 B0[4], B1[4], B2[4];

    // Advance state through chunks m+1..c-1 (no stores), pipelined.
    {
        const int ia = ((m + 1) * CH) >> 1;
        const int ibx = (c * CH) >> 1;
        const int nb = (ibx - ia) >> 2;    // multiple of 8 (or 0)
        const float4* bp = rp + ia;
        float& shi = sms;                  // CBW advances "shi"
        PIPE3(nb, CBW);
    }

    // Recompute chunk c exactly, with stores, pipelined.
    {
        const int ib0 = (c * CH) >> 1;     // float2 output base index
        const float4* bp = rp + ib0;
        PIPE3(8, CBF);
    }

    if (c == NC - 1) {                     // rewrite the t=0 wraparound output
        float4 f0 = rp[0];
        float ss = sms, gg = gw;
        orow[0] = step(f0.x, f0.y, ss, gg, p);
    }
}

// Fallback: monolithic sequential (odd shapes / tiny workspace).
template<int T>
__global__ __launch_bounds__(64, 1)
void hir_scan_kernel(const float* __restrict__ inputs,
                     const float* __restrict__ pINSC,  const float* __restrict__ pCOEFF,
                     const float* __restrict__ pSQ,    const float* __restrict__ pSMSC,
                     const float* __restrict__ pSUB,   const float* __restrict__ pCRAK,
                     const float* __restrict__ pRecK,
                     float* __restrict__ out, int B)
{
    int b = blockIdx.x * blockDim.x + threadIdx.x;
    if (b >= B) return;
    P p = make_params(pINSC, pCOEFF, pSQ, pSMSC, pSUB, pCRAK, pRecK);
    const float4* __restrict__ rp = (const float4*)(inputs + (size_t)b * (2 * T));
    float* __restrict__ orow = out + (size_t)b * T;
    float sms = 0.0f, gw = 0.0f;
    float4 cur = rp[0];
    const float P0 = cur.x, E0 = cur.y;
    constexpr int NI = T / 2;
    for (int i = 0; i < NI; ++i) {
        int ni = (i + 1 < NI) ? (i + 1) : i;
        float4 nxt = rp[ni];
        float qa = step(cur.x, cur.y, sms, gw, p);
        float qb = step(cur.z, cur.w, sms, gw, p);
        if (i == 0) { orow[1] = qb; }
        else        { ((float2*)orow)[i] = make_float2(qa, qb); }
        cur = nxt;
    }
    float ss = sms, gg = gw;
    orow[0] = step(P0, E0, ss, gg, p);
}

extern "C" void kernel_launch(void* const* d_in, const int* in_sizes, int n_in,
                              void* d_out, int out_size, void* d_ws, size_t ws_size,
                              hipStream_t stream) {
    (void)n_in; (void)out_size;
    constexpr int T  = 1024;
    constexpr int NC = 16;    // chunks (CH=64)
    constexpr int W  = 320;   // warm-up: gap ~250*e^(-.0201*320) ~ 0.4 < 0.75
    const float* inputs = (const float*)d_in[0];
    const float* INSC   = (const float*)d_in[1];
    const float* COEFF  = (const float*)d_in[2];
    const float* SQ     = (const float*)d_in[3];
    const float* SMSC   = (const float*)d_in[4];
    const float* SUB    = (const float*)d_in[5];
    const float* CRAK   = (const float*)d_in[6];
    const float* RecK   = (const float*)d_in[7];
    float* out = (float*)d_out;

    int B = in_sizes[0] / (2 * T);            // 4096 for the reference shape
    size_t stBytes = (size_t)B * NC * sizeof(float4);   // 1 MB

    if ((B % 64) == 0 && ws_size >= stBytes) {
        float4* st = (float4*)d_ws;
        long total = (long)B * NC;            // 65536 threads = 1024 waves
        int blocks = (int)((total + 63) / 64);
        hir_pass1<T, NC, W><<<dim3(blocks), dim3(64), 0, stream>>>(
            inputs, INSC, COEFF, SQ, SMSC, SUB, CRAK, RecK, out, st, B);
        hir_fixup<T, NC><<<dim3(blocks), dim3(64), 0, stream>>>(
            inputs, INSC, COEFF, SQ, SMSC, SUB, CRAK, RecK, out, st, B);
        return;
    }

    int blocks = (B + 63) / 64;
    hir_scan_kernel<T><<<dim3(blocks), dim3(64), 0, stream>>>(
        inputs, INSC, COEFF, SQ, SMSC, SUB, CRAK, RecK, out, B);
}